// Round 6
// baseline (1579.126 us; speedup 1.0000x reference)
//
#include <hip/hip_runtime.h>
#include <cstdint>
#include <cstddef>
#include <cstring>

typedef __bf16 bf16x8 __attribute__((ext_vector_type(8)));
typedef float f32x4 __attribute__((ext_vector_type(4)));
typedef unsigned short ushortx8 __attribute__((ext_vector_type(8)));

// float -> bf16, round-half-up
__device__ __forceinline__ unsigned short f2bf(float f) {
  union { float f; unsigned int u; } v; v.f = f;
  return (unsigned short)((v.u + 0x8000u) >> 16);
}

__device__ __forceinline__ bf16x8 pun8(ushortx8 u) {
  union { ushortx8 u; bf16x8 b; } p; p.u = u; return p.b;
}

// GELU via sigmoid identity (verified in prior rounds)
__device__ __forceinline__ float gelu_s(float x) {
  float x2 = x * x;
  float p = __builtin_fmaf(x2, -0.10294324f, -2.30220819f);
  float e = __builtin_amdgcn_exp2f(x * p);
  return x * __builtin_amdgcn_rcpf(1.0f + e);
}

// async global->LDS, 16B/lane. LDS dest is wave-uniform base + lane*16.
#define GLOAD16(gsrc, ldst)                                                  \
  __builtin_amdgcn_global_load_lds(                                          \
      (const __attribute__((address_space(1))) unsigned int*)(gsrc),         \
      (__attribute__((address_space(3))) unsigned int*)(uintptr_t)(          \
          (char*)(ldst)),                                                    \
      16, 0, 0)

// Swizzled tile: 16B chunk (row R, col8 C in [0,8)) at
// (R>>5)*4096 + ((R&31)*8 + (C ^ (R&7)))*16. Chunk (R,c8d) holds global
// col8 (c8d ^ (R&7)); SWZ_FRAG(R,C8) therefore returns global col C8.
#define SWZ_FRAG(base, R, C8)                                                \
  (*(const bf16x8*)((base) + (((R) >> 5) * 4096) +                           \
                    ((((R)&31) * 8 + ((C8) ^ ((R)&7))) * 16)))

// A-tile staging: z (f32) -> reg -> bf16 -> swizzled LDS (same bytes as the
// old GLOAD16-from-zb path).
__device__ __forceinline__ void stage_A_f32(const float* __restrict__ ag,
                                            char* lds, int tid, int ko) {
  f32x4 a0[4], a1[4];
#pragma unroll
  for (int it = 0; it < 4; ++it) {
    const float* p = ag + it * 32 * 512 + ko;
    a0[it] = *(const f32x4*)(p);
    a1[it] = *(const f32x4*)(p + 4);
  }
#pragma unroll
  for (int it = 0; it < 4; ++it) {
    ushortx8 r;
    r[0] = f2bf(a0[it][0]); r[1] = f2bf(a0[it][1]);
    r[2] = f2bf(a0[it][2]); r[3] = f2bf(a0[it][3]);
    r[4] = f2bf(a1[it][0]); r[5] = f2bf(a1[it][1]);
    r[6] = f2bf(a1[it][2]); r[7] = f2bf(a1[it][3]);
    *(ushortx8*)(lds + it * 4096 + tid * 16) = r;
  }
}

// ---------------------------------------------------------------------------
// Expert tile. B from w1t (fast, GLOAD16) when ready; else self-staged from
// W1 f32 (bitwise-identical LDS bytes; no cross-block dependency).
// ---------------------------------------------------------------------------
__device__ __forceinline__ void expert_tile(
    int e, int mbase, bool ready, const float* __restrict__ z,
    const float* __restrict__ W1, const unsigned short* __restrict__ w1t,
    const float* __restrict__ b1, const float* __restrict__ w2,
    const float* __restrict__ b2, float* __restrict__ out, char* lds, int tid,
    int wq, int l15, int l4, int c8s) {
  char* ldsB = lds + 16384;
  const float* ag = z + (size_t)(mbase + (tid >> 3)) * 512 + c8s;
  const unsigned short* bg = w1t + e * 65536 + (tid >> 3) * 512 + c8s;
  const int wr = wq >> 1;  // row half of this wave
  const int wc = wq & 1;   // col half of this wave
  f32x4 acc[4][4] = {};
  for (int kt = 0; kt < 8; ++kt) {
    const int ko = kt * 64;
    if (ready) {
#pragma unroll
      for (int it = 0; it < 4; ++it)
        GLOAD16(bg + it * 32 * 512 + ko, ldsB + it * 4096 + tid * 16);
    } else {
      // self-stage: chunk c -> row R=c>>3 (h), dest col8 c8d=c&7,
      // global d = ko + (c8d^(R&7))*8 + j, source W1[e][d][R].
#pragma unroll
      for (int i = 0; i < 4; ++i) {
        int c = tid + 256 * i;
        int R = c >> 3, c8 = c & 7;
        int dbase = ko + ((c8 ^ (R & 7)) * 8);
        const float* src = W1 + ((size_t)e << 16) + (size_t)dbase * 128 + R;
        ushortx8 v;
#pragma unroll
        for (int j = 0; j < 8; ++j) v[j] = f2bf(src[j * 128]);
        *(ushortx8*)(ldsB + (R >> 5) * 4096 + ((R & 31) * 8 + c8) * 16) = v;
      }
    }
    stage_A_f32(ag, lds, tid, ko);
    __syncthreads();
#pragma unroll
    for (int ks = 0; ks < 2; ++ks) {
      bf16x8 af[4];
#pragma unroll
      for (int rt = 0; rt < 4; ++rt)
        af[rt] = SWZ_FRAG(lds, wr * 64 + rt * 16 + l15, ks * 4 + l4);
#pragma unroll
      for (int ct = 0; ct < 4; ++ct) {
        bf16x8 bfv = SWZ_FRAG(ldsB, wc * 64 + ct * 16 + l15, ks * 4 + l4);
#pragma unroll
        for (int rt = 0; rt < 4; ++rt)
          acc[rt][ct] = __builtin_amdgcn_mfma_f32_16x16x32_bf16(
              af[rt], bfv, acc[rt][ct], 0, 0, 0);
      }
    }
    __syncthreads();
  }
  // epilogue: partial y over this wave's 64 cols, cross-wave combine
  float b1v[4], w2v[4];
#pragma unroll
  for (int ct = 0; ct < 4; ++ct) {
    int n = wc * 64 + ct * 16 + l15;
    b1v[ct] = b1[e * 128 + n];
    w2v[ct] = w2[e * 128 + n];
  }
  float* ylds = (float*)(lds + 32768);  // [4 waves][64 rows]
#pragma unroll
  for (int rt = 0; rt < 4; ++rt) {
#pragma unroll
    for (int i = 0; i < 4; ++i) {
      float s = 0.0f;
#pragma unroll
      for (int ct = 0; ct < 4; ++ct)
        s += gelu_s(acc[rt][ct][i] + b1v[ct]) * w2v[ct];
#pragma unroll
      for (int off = 1; off < 16; off <<= 1) s += __shfl_xor(s, off, 16);
      if (l15 == 0) ylds[wq * 64 + rt * 16 + l4 * 4 + i] = s;
    }
  }
  __syncthreads();
  if (tid < 128) {
    int rl = tid & 63, half = tid >> 6;
    float y = ylds[half * 128 + rl] + ylds[half * 128 + 64 + rl] + b2[e];
    out[(size_t)2097152 + (size_t)(mbase + half * 64 + rl) * 16 + e] = y;
  }
}

// ---------------------------------------------------------------------------
// Logits tile. Wc read directly as f32 (strided, 32KB L2-hot) — no wct, no
// dependency on converters.
// ---------------------------------------------------------------------------
__device__ __forceinline__ void logits_tile(
    int mbase, const float* __restrict__ z, const float* __restrict__ Wc,
    const float* __restrict__ bc, float* __restrict__ out, char* lds, int tid,
    int wq, int l15, int l4, int c8s) {
  const float* ag = z + (size_t)(mbase + (tid >> 3)) * 512 + c8s;
  f32x4 acc2[2] = {};
  for (int kt = 0; kt < 8; ++kt) {
    const int ko = kt * 64;
    stage_A_f32(ag, lds, tid, ko);
    ushortx8 u0, u1;
#pragma unroll
    for (int j = 0; j < 8; ++j) {
      u0[j] = f2bf(Wc[(ko + l4 * 8 + j) * 16 + l15]);
      u1[j] = f2bf(Wc[(ko + 32 + l4 * 8 + j) * 16 + l15]);
    }
    bf16x8 bfr0 = pun8(u0), bfr1 = pun8(u1);
    __syncthreads();
#pragma unroll
    for (int rt = 0; rt < 2; ++rt) {
      bf16x8 a0 = SWZ_FRAG(lds, wq * 32 + rt * 16 + l15, l4);
      acc2[rt] =
          __builtin_amdgcn_mfma_f32_16x16x32_bf16(a0, bfr0, acc2[rt], 0, 0, 0);
      bf16x8 a1 = SWZ_FRAG(lds, wq * 32 + rt * 16 + l15, 4 + l4);
      acc2[rt] =
          __builtin_amdgcn_mfma_f32_16x16x32_bf16(a1, bfr1, acc2[rt], 0, 0, 0);
    }
    __syncthreads();
  }
  float bcv = bc[l15];
#pragma unroll
  for (int rt = 0; rt < 2; ++rt) {
#pragma unroll
    for (int i = 0; i < 4; ++i) {
      int row = wq * 32 + rt * 16 + l4 * 4 + i;
      float lg = acc2[rt][i] + bcv;
      float mx = lg;
#pragma unroll
      for (int off = 1; off < 16; off <<= 1)
        mx = fmaxf(mx, __shfl_xor(mx, off, 16));
      float ex = __expf(lg - mx);
      float sm = ex;
#pragma unroll
      for (int off = 1; off < 16; off <<= 1) sm += __shfl_xor(sm, off, 16);
      size_t ro = (size_t)(mbase + row) * 16 + l15;
      out[ro] = lg;                 // logits
      out[1048576 + ro] = ex / sm;  // p_g
    }
  }
}

// ---------------------------------------------------------------------------
// Single fused kernel, 9728 blocks:
//   bid < 1024 : converter block — W1[g,d,h] -> w1t[g,h,d] bf16 (32x32 LDS
//                tile), then threadfence + atomicAdd(done). Cheap, retires
//                fast.
//   bid >= 1024: tile block, round-5 static mapping on tb = bid-1024:
//                xcd = tb&7, t = tb>>3, panel = xcd*64 + t/17, r = t%17.
//                r==0 -> logits; else expert e=r-1. Non-blocking readiness
//                check picks w1t fast path vs self-stage-from-W1 slow path —
//                correct under ANY dispatch order (no spin, no deadlock).
// ---------------------------------------------------------------------------
__global__ __launch_bounds__(256, 4) void k_fused(
    const float* __restrict__ z, const float* __restrict__ W1,
    const float* __restrict__ Wc, const float* __restrict__ bc,
    const float* __restrict__ b1, const float* __restrict__ w2,
    const float* __restrict__ b2, unsigned short* __restrict__ w1t,
    int* __restrict__ done, float* __restrict__ out) {
  __shared__ alignas(16) char lds[33792];
  __shared__ int s_rdy;
  const int tid = threadIdx.x;
  const int bid = blockIdx.x;

  if (bid < 1024) {
    // ---- converter: W1 transpose via 32x32 LDS tile, both sides coalesced
    float* tile = (float*)lds;  // [32][33]
    int gg = bid >> 6;
    int t6 = bid & 63;  // 16 d-blk x 4 h-blk
    int d0 = (t6 >> 2) * 32;
    int h0 = (t6 & 3) * 32;
    int tx = tid & 31, ty = tid >> 5;
#pragma unroll
    for (int r = 0; r < 4; ++r)
      tile[(r * 8 + ty) * 33 + tx] =
          W1[(gg << 16) + (d0 + r * 8 + ty) * 128 + h0 + tx];
    __syncthreads();
#pragma unroll
    for (int r = 0; r < 4; ++r)
      w1t[(gg << 16) + (h0 + r * 8 + ty) * 512 + d0 + tx] =
          f2bf(tile[tx * 33 + r * 8 + ty]);
    __syncthreads();
    __threadfence();  // release: w1t visible device-wide before count
    if (tid == 0) atomicAdd(done, 1);
    return;
  }

  const int wq = tid >> 6;
  const int l15 = tid & 15;
  const int l4 = (tid >> 4) & 3;
  const int c8s = (((tid & 7) ^ ((tid >> 3) & 7))) * 8;
  const int tb = bid - 1024;
  const int xcd = tb & 7;
  const int t = tb >> 3;         // 0..1087
  const int pl = t / 17;         // panel-local 0..63
  const int r = t - pl * 17;     // 0..16
  const int mbase = (xcd * 64 + pl) * 128;

  if (r == 0) {
    logits_tile(mbase, z, Wc, bc, out, lds, tid, wq, l15, l4, c8s);
  } else {
    if (tid == 0) s_rdy = (atomicAdd(done, 0) >= 1024) ? 1 : 0;
    __syncthreads();
    bool ready = (s_rdy != 0);
    if (ready) __threadfence();  // acquire: order w1t reads after the count
    expert_tile(r - 1, mbase, ready, z, W1, w1t, b1, w2, b2, out, lds, tid,
                wq, l15, l4, c8s);
  }
}

// ---------------------------------------------------------------------------
extern "C" void kernel_launch(void* const* d_in, const int* in_sizes, int n_in,
                              void* d_out, int out_size, void* d_ws,
                              size_t ws_size, hipStream_t stream) {
  const float* z = (const float*)d_in[0];
  const float* Wc = (const float*)d_in[1];
  const float* bc = (const float*)d_in[2];
  const float* W1 = (const float*)d_in[3];
  const float* b1 = (const float*)d_in[4];
  const float* W2 = (const float*)d_in[5];
  const float* b2 = (const float*)d_in[6];
  float* out = (float*)d_out;

  unsigned short* w1t = (unsigned short*)d_ws;           // 2 MB
  int* done = (int*)(w1t + (size_t)16 * 128 * 512);      // 4 B

  hipMemsetAsync(done, 0, 4, stream);  // capture-safe (harness uses it too)
  k_fused<<<1024 + 8 * 1088, 256, 0, stream>>>(z, W1, Wc, bc, b1, W2, b2, w1t,
                                               done, out);
}

// Round 7
// 579.403 us; speedup vs baseline: 2.7254x; 2.7254x over previous
//
#include <hip/hip_runtime.h>
#include <hip/hip_cooperative_groups.h>
#include <cstdint>
#include <cstddef>

namespace cg = cooperative_groups;

typedef __bf16 bf16x8 __attribute__((ext_vector_type(8)));
typedef float f32x4 __attribute__((ext_vector_type(4)));
typedef unsigned short ushortx8 __attribute__((ext_vector_type(8)));

// float -> bf16, round-half-up
__device__ __forceinline__ unsigned short f2bf(float f) {
  union { float f; unsigned int u; } v; v.f = f;
  return (unsigned short)((v.u + 0x8000u) >> 16);
}

// GELU via sigmoid identity (verified in prior rounds)
__device__ __forceinline__ float gelu_s(float x) {
  float x2 = x * x;
  float p = __builtin_fmaf(x2, -0.10294324f, -2.30220819f);
  float e = __builtin_amdgcn_exp2f(x * p);
  return x * __builtin_amdgcn_rcpf(1.0f + e);
}

// async global->LDS, 16B/lane. LDS dest is wave-uniform base + lane*16.
#define GLOAD16(gsrc, ldst)                                                  \
  __builtin_amdgcn_global_load_lds(                                          \
      (const __attribute__((address_space(1))) unsigned int*)(gsrc),         \
      (__attribute__((address_space(3))) unsigned int*)(uintptr_t)(          \
          (char*)(ldst)),                                                    \
      16, 0, 0)

// Swizzled tile: 16B chunk (row R, col8 C in [0,8)) at
// (R>>5)*4096 + ((R&31)*8 + (C ^ (R&7)))*16.
#define SWZ_FRAG(base, R, C8)                                                \
  (*(const bf16x8*)((base) + (((R) >> 5) * 4096) +                           \
                    ((((R)&31) * 8 + ((C8) ^ ((R)&7))) * 16)))

// A-tile staging: z (f32) -> reg -> bf16 -> swizzled LDS (proven round 5).
__device__ __forceinline__ void stage_A_f32(const float* __restrict__ ag,
                                            char* lds, int tid, int ko) {
  f32x4 a0[4], a1[4];
#pragma unroll
  for (int it = 0; it < 4; ++it) {
    const float* p = ag + it * 32 * 512 + ko;
    a0[it] = *(const f32x4*)(p);
    a1[it] = *(const f32x4*)(p + 4);
  }
#pragma unroll
  for (int it = 0; it < 4; ++it) {
    ushortx8 r;
    r[0] = f2bf(a0[it][0]); r[1] = f2bf(a0[it][1]);
    r[2] = f2bf(a0[it][2]); r[3] = f2bf(a0[it][3]);
    r[4] = f2bf(a1[it][0]); r[5] = f2bf(a1[it][1]);
    r[6] = f2bf(a1[it][2]); r[7] = f2bf(a1[it][3]);
    *(ushortx8*)(lds + it * 4096 + tid * 16) = r;
  }
}

// ---------------------------------------------------------------------------
// Tile bodies — byte-identical math to the passing round-5 kernel.
// ---------------------------------------------------------------------------
__device__ __forceinline__ void expert_tile(
    int e, int mbase, const float* __restrict__ z,
    const unsigned short* __restrict__ w1t, const float* __restrict__ b1,
    const float* __restrict__ w2, const float* __restrict__ b2,
    float* __restrict__ out, char* lds, int tid, int wq, int l15, int l4,
    int c8s) {
  char* ldsB = lds + 16384;
  const float* ag = z + (size_t)(mbase + (tid >> 3)) * 512 + c8s;
  const unsigned short* bg = w1t + e * 65536 + (tid >> 3) * 512 + c8s;
  const int wr = wq >> 1;  // row half of this wave
  const int wc = wq & 1;   // col half of this wave
  f32x4 acc[4][4] = {};
  for (int kt = 0; kt < 8; ++kt) {
    const int ko = kt * 64;
#pragma unroll
    for (int it = 0; it < 4; ++it)
      GLOAD16(bg + it * 32 * 512 + ko, ldsB + it * 4096 + tid * 16);
    stage_A_f32(ag, lds, tid, ko);
    __syncthreads();
#pragma unroll
    for (int ks = 0; ks < 2; ++ks) {
      bf16x8 af[4];
#pragma unroll
      for (int rt = 0; rt < 4; ++rt)
        af[rt] = SWZ_FRAG(lds, wr * 64 + rt * 16 + l15, ks * 4 + l4);
#pragma unroll
      for (int ct = 0; ct < 4; ++ct) {
        bf16x8 bfv = SWZ_FRAG(ldsB, wc * 64 + ct * 16 + l15, ks * 4 + l4);
#pragma unroll
        for (int rt = 0; rt < 4; ++rt)
          acc[rt][ct] = __builtin_amdgcn_mfma_f32_16x16x32_bf16(
              af[rt], bfv, acc[rt][ct], 0, 0, 0);
      }
    }
    __syncthreads();
  }
  // epilogue: partial y over this wave's 64 cols, cross-wave combine
  float b1v[4], w2v[4];
#pragma unroll
  for (int ct = 0; ct < 4; ++ct) {
    int n = wc * 64 + ct * 16 + l15;
    b1v[ct] = b1[e * 128 + n];
    w2v[ct] = w2[e * 128 + n];
  }
  float* ylds = (float*)(lds + 32768);  // [4 waves][64 rows]
#pragma unroll
  for (int rt = 0; rt < 4; ++rt) {
#pragma unroll
    for (int i = 0; i < 4; ++i) {
      float s = 0.0f;
#pragma unroll
      for (int ct = 0; ct < 4; ++ct)
        s += gelu_s(acc[rt][ct][i] + b1v[ct]) * w2v[ct];
#pragma unroll
      for (int off = 1; off < 16; off <<= 1) s += __shfl_xor(s, off, 16);
      if (l15 == 0) ylds[wq * 64 + rt * 16 + l4 * 4 + i] = s;
    }
  }
  __syncthreads();
  if (tid < 128) {
    int rl = tid & 63, half = tid >> 6;
    float y = ylds[half * 128 + rl] + ylds[half * 128 + 64 + rl] + b2[e];
    out[(size_t)2097152 + (size_t)(mbase + half * 64 + rl) * 16 + e] = y;
  }
  // NOTE (persistent reuse): next tile writes lds[0..32K); ylds reads are in
  // [32K..33K) — disjoint, no barrier needed between loop iterations.
}

__device__ __forceinline__ void logits_tile(
    int mbase, const float* __restrict__ z,
    const unsigned short* __restrict__ wct, const float* __restrict__ bc,
    float* __restrict__ out, char* lds, int tid, int wq, int l15, int l4,
    int c8s) {
  const float* ag = z + (size_t)(mbase + (tid >> 3)) * 512 + c8s;
  const unsigned short* wb = wct + l15 * 512 + l4 * 8;  // direct, L2-hot
  f32x4 acc2[2] = {};
  for (int kt = 0; kt < 8; ++kt) {
    const int ko = kt * 64;
    stage_A_f32(ag, lds, tid, ko);
    bf16x8 bfr0 = *(const bf16x8*)(wb + ko);
    bf16x8 bfr1 = *(const bf16x8*)(wb + ko + 32);
    __syncthreads();
#pragma unroll
    for (int rt = 0; rt < 2; ++rt) {
      bf16x8 a0 = SWZ_FRAG(lds, wq * 32 + rt * 16 + l15, l4);
      acc2[rt] =
          __builtin_amdgcn_mfma_f32_16x16x32_bf16(a0, bfr0, acc2[rt], 0, 0, 0);
      bf16x8 a1 = SWZ_FRAG(lds, wq * 32 + rt * 16 + l15, 4 + l4);
      acc2[rt] =
          __builtin_amdgcn_mfma_f32_16x16x32_bf16(a1, bfr1, acc2[rt], 0, 0, 0);
    }
    __syncthreads();
  }
  float bcv = bc[l15];
#pragma unroll
  for (int rt = 0; rt < 2; ++rt) {
#pragma unroll
    for (int i = 0; i < 4; ++i) {
      int row = wq * 32 + rt * 16 + l4 * 4 + i;
      float lg = acc2[rt][i] + bcv;
      float mx = lg;
#pragma unroll
      for (int off = 1; off < 16; off <<= 1)
        mx = fmaxf(mx, __shfl_xor(mx, off, 16));
      float ex = __expf(lg - mx);
      float sm = ex;
#pragma unroll
      for (int off = 1; off < 16; off <<= 1) sm += __shfl_xor(sm, off, 16);
      size_t ro = (size_t)(mbase + row) * 16 + l15;
      out[ro] = lg;                 // logits
      out[1048576 + ro] = ex / sm;  // p_g
    }
  }
}

// ---------------------------------------------------------------------------
// Cooperative single-launch kernel.
// Phase 1 (static split, ~6 MB): jobs 0..1023 = W1[g,d,h]->w1t[g,h,d] 32x32
//   tiles; jobs 1024..1055 = Wc->wct chunks. No z conversion (z consumed
//   directly as f32 by the tile bodies — proven round 5).
// threadfence + grid.sync (cross-XCD visibility of w1t/wct). No flags, no
// memset, nothing else in the stream.
// Phase 2: static persistent loop over round-5's exact mapping:
//   v in {p, p+NB, ...} < 8704; xcd=v&7, t=v>>3, panel=xcd*64+t/17, r=t%17;
//   r==0 logits, else expert r-1. Stride NB (multiple of 8) preserves the
//   v&7 XCD grouping; the 17-tile period cycles residues -> balanced mix.
// ---------------------------------------------------------------------------
__global__ __launch_bounds__(256, 4) void k_coop(
    const float* __restrict__ z, const float* __restrict__ W1,
    const float* __restrict__ Wc, const float* __restrict__ bc,
    const float* __restrict__ b1, const float* __restrict__ w2,
    const float* __restrict__ b2, unsigned short* __restrict__ w1t,
    unsigned short* __restrict__ wct, float* __restrict__ out) {
  __shared__ alignas(16) char lds[33792];
  const int NB = gridDim.x;
  const int p = blockIdx.x;
  const int tid = threadIdx.x;

  // ---- phase 1 ----
  for (int j = p; j < 1056; j += NB) {
    if (j < 1024) {
      float* tile = (float*)lds;  // [32][33]
      int gg = j >> 6;
      int t6 = j & 63;  // 16 d-blk x 4 h-blk
      int d0 = (t6 >> 2) * 32;
      int h0 = (t6 & 3) * 32;
      int tx = tid & 31, ty = tid >> 5;
#pragma unroll
      for (int r = 0; r < 4; ++r)
        tile[(r * 8 + ty) * 33 + tx] =
            W1[(gg << 16) + (d0 + r * 8 + ty) * 128 + h0 + tx];
      __syncthreads();
#pragma unroll
      for (int r = 0; r < 4; ++r)
        w1t[(gg << 16) + (h0 + r * 8 + ty) * 512 + d0 + tx] =
            f2bf(tile[tx * 33 + r * 8 + ty]);
      __syncthreads();
    } else {
      int i = (j - 1024) * 256 + tid;
      wct[(i & 15) * 512 + (i >> 4)] = f2bf(Wc[i]);
    }
  }

  __threadfence();  // release w1t/wct device-wide
  cg::this_grid().sync();
  __threadfence();  // acquire

  // ---- phase 2: static persistent tile loop ----
  const int wq = tid >> 6;
  const int l15 = tid & 15;
  const int l4 = (tid >> 4) & 3;
  const int c8s = (((tid & 7) ^ ((tid >> 3) & 7))) * 8;
  for (int v = p; v < 8704; v += NB) {
    const int xcd = v & 7;
    const int t = v >> 3;       // 0..1087
    const int pl = t / 17;      // panel-local 0..63
    const int r = t - pl * 17;  // 0..16
    const int mbase = (xcd * 64 + pl) * 128;
    if (r == 0)
      logits_tile(mbase, z, wct, bc, out, lds, tid, wq, l15, l4, c8s);
    else
      expert_tile(r - 1, mbase, z, w1t, b1, w2, b2, out, lds, tid, wq, l15,
                  l4, c8s);
  }
}

// ---------------------------------------------------------------------------
// Fallback (proven round-5 path, 353 us) if cooperative launch unavailable.
// ---------------------------------------------------------------------------
__global__ __launch_bounds__(256) void k_convert(
    const float* __restrict__ W1, const float* __restrict__ Wc,
    unsigned short* __restrict__ w1t, unsigned short* __restrict__ wct) {
  int bid = blockIdx.x;
  int tid = threadIdx.x;
  if (bid < 1024) {
    __shared__ float tile[32][33];
    int gg = bid >> 6;
    int t = bid & 63;
    int d0 = (t >> 2) * 32;
    int h0 = (t & 3) * 32;
    int tx = tid & 31, ty = tid >> 5;
#pragma unroll
    for (int r = 0; r < 4; ++r)
      tile[r * 8 + ty][tx] = W1[(gg << 16) + (d0 + r * 8 + ty) * 128 + h0 + tx];
    __syncthreads();
#pragma unroll
    for (int r = 0; r < 4; ++r)
      w1t[(gg << 16) + (h0 + r * 8 + ty) * 512 + d0 + tx] =
          f2bf(tile[tx][r * 8 + ty]);
  } else {
#pragma unroll
    for (int j = 0; j < 32; ++j) {
      int i = j * 256 + tid;
      wct[(i & 15) * 512 + (i >> 4)] = f2bf(Wc[i]);
    }
  }
}

__global__ __launch_bounds__(256, 4) void k_main(
    const float* __restrict__ z, const unsigned short* __restrict__ w1t,
    const unsigned short* __restrict__ wct, const float* __restrict__ bc,
    const float* __restrict__ b1, const float* __restrict__ w2,
    const float* __restrict__ b2, float* __restrict__ out) {
  __shared__ alignas(16) char lds[33792];
  const int tid = threadIdx.x;
  const int wq = tid >> 6;
  const int l15 = tid & 15;
  const int l4 = (tid >> 4) & 3;
  const int c8s = (((tid & 7) ^ ((tid >> 3) & 7))) * 8;
  const int xcd = blockIdx.x & 7;
  const int t = blockIdx.x >> 3;
  const int pl = t / 17;
  const int r = t - pl * 17;
  const int mbase = (xcd * 64 + pl) * 128;
  if (r == 0)
    logits_tile(mbase, z, wct, bc, out, lds, tid, wq, l15, l4, c8s);
  else
    expert_tile(r - 1, mbase, z, w1t, b1, w2, b2, out, lds, tid, wq, l15, l4,
                c8s);
}

// ---------------------------------------------------------------------------
extern "C" void kernel_launch(void* const* d_in, const int* in_sizes, int n_in,
                              void* d_out, int out_size, void* d_ws,
                              size_t ws_size, hipStream_t stream) {
  const float* z = (const float*)d_in[0];
  const float* Wc = (const float*)d_in[1];
  const float* bc = (const float*)d_in[2];
  const float* W1 = (const float*)d_in[3];
  const float* b1 = (const float*)d_in[4];
  const float* W2 = (const float*)d_in[5];
  const float* b2 = (const float*)d_in[6];
  float* out = (float*)d_out;

  unsigned short* w1t = (unsigned short*)d_ws;           // 2 MB
  unsigned short* wct = w1t + (size_t)16 * 128 * 512;    // 16 KB

  int dev = 0;
  (void)hipGetDevice(&dev);
  int coop = 0;
  (void)hipDeviceGetAttribute(&coop, hipDeviceAttributeCooperativeLaunch, dev);
  int ncu = 0;
  (void)hipDeviceGetAttribute(&ncu, hipDeviceAttributeMultiprocessorCount,
                              dev);
  int maxb = 0;
  (void)hipOccupancyMaxActiveBlocksPerMultiprocessor(&maxb, k_coop, 256, 0);
  int NB = maxb * (ncu > 0 ? ncu : 256);
  if (NB > 1024) NB = 1024;
  NB &= ~7;

  bool ok = false;
  if (coop && NB >= 8) {
    void* kargs[] = {(void*)&z,  (void*)&W1,  (void*)&Wc,  (void*)&bc,
                     (void*)&b1, (void*)&W2,  (void*)&b2,  (void*)&w1t,
                     (void*)&wct, (void*)&out};
    hipError_t err = hipLaunchCooperativeKernel(
        (const void*)k_coop, dim3(NB), dim3(256), kargs, 0, stream);
    ok = (err == hipSuccess);
  }
  if (!ok) {
    k_convert<<<1024 + 1, 256, 0, stream>>>(W1, Wc, w1t, wct);
    k_main<<<8 * 1088, 256, 0, stream>>>(z, w1t, wct, bc, b1, W2, b2, out);
  }
}